// Round 10
// baseline (500.662 us; speedup 1.0000x reference)
//
#include <hip/hip_runtime.h>
#include <hip/hip_bf16.h>
#include <math.h>

#define HID 256

typedef __attribute__((ext_vector_type(8))) short bf16x8;
typedef __attribute__((ext_vector_type(4))) float f32x4;

__device__ __forceinline__ short f2bf(float x) {
    __hip_bfloat16 h = __float2bfloat16(x);
    union { __hip_bfloat16 b; short s; } u; u.b = h; return u.s;
}
__device__ __forceinline__ float bf2f(short s) {
    union { short s; __hip_bfloat16 b; } u; u.s = s; return __bfloat162float(u.b);
}

// ---------- W -> W^T split into hi/lo bf16 -------------------------------
// out layout per matrix m: hi at m*131072 + n*256 + k, lo at +65536.
__global__ __launch_bounds__(256) void convw_kernel(const float* __restrict__ W0,
                                                    const float* __restrict__ W1,
                                                    const float* __restrict__ W2,
                                                    short* __restrict__ outb) {
    const int m = blockIdx.x >> 8;
    const int n = blockIdx.x & 255;
    const int k = threadIdx.x;
    const float* W = (m == 0) ? W0 : (m == 1) ? W1 : W2;
    const float x = W[k * HID + n];
    const short hi = f2bf(x);
    const short lo = f2bf(x - bf2f(hi));
    short* o = outb + (size_t)m * 131072;
    o[n * HID + k] = hi;
    o[65536 + n * HID + k] = lo;
}

// ---------- GEMM via bf16 split MFMA, A+B LDS-staged ---------------------
// C[Mx256] = A[Mx256] @ W. 128-row block, 512 threads = 8 waves (4M x 2N),
// wave tile 32x128, 16x16x32 MFMA.
// TERMS==3: ah*bh + al*bh + ah*bl (q/o projections, full split precision)
// TERMS==2: ah*bh + ah*bl (k/v: output is rounded to bf16 anyway)
// Output: Cf fp32 (+bias)  OR  kvout bf16 interleaved kv rows (part 0=k,1=v).
template <int TERMS>
__global__ __launch_bounds__(512, 4) void gemm_mfma_t(const float* __restrict__ A,
                                                      const short* __restrict__ Wt,
                                                      const float* __restrict__ bias,
                                                      float* __restrict__ Cf,
                                                      short* __restrict__ kvout,
                                                      int part, int M) {
    __shared__ short Ahi[128][40];
    __shared__ short Alo[(TERMS == 3) ? 128 : 1][40];
    __shared__ short Bhi[256][40];
    __shared__ short Blo[256][40];
    const int tid  = threadIdx.x;
    const int lane = tid & 63;
    const int wave = tid >> 6;      // 0..7
    const int wm   = wave >> 1;     // 0..3 (M quarter)
    const int wn   = wave & 1;      // 0..1 (N half)
    const int row0 = blockIdx.x * 128;

    // A staging: thread covers 8 k of one row
    const int srow = tid >> 2;          // 0..127
    const int scol = (tid & 3) * 8;     // 0,8,16,24
    const int arow = row0 + srow;
    const bool aok = arow < M;
    const float* aptr = A + (size_t)arow * HID + scol;

    // B staging: thread covers 16 k of one col (hi and lo)
    const int bn = tid >> 1;            // 0..255
    const int bk = (tid & 1) * 16;      // 0,16
    const short* bhp = Wt + bn * HID + bk;
    const short* blp = bhp + 65536;

    f32x4 acc[2][8];
#pragma unroll
    for (int i = 0; i < 2; ++i)
#pragma unroll
        for (int j = 0; j < 8; ++j) acc[i][j] = (f32x4){0.f, 0.f, 0.f, 0.f};

    const int l15 = lane & 15;
    const int akk = (lane >> 4) * 8;    // 0,8,16,24

    // prefetch first K-tile into regs
    float4 x0 = make_float4(0.f, 0.f, 0.f, 0.f), x1 = x0;
    if (aok) { x0 = *(const float4*)(aptr); x1 = *(const float4*)(aptr + 4); }
    bf16x8 pb0 = *(const bf16x8*)(bhp);
    bf16x8 pb1 = *(const bf16x8*)(bhp + 8);
    bf16x8 pb2 = *(const bf16x8*)(blp);
    bf16x8 pb3 = *(const bf16x8*)(blp + 8);

    for (int k0 = 0; k0 < HID; k0 += 32) {
        __syncthreads();    // prior iteration's LDS reads complete
        {
            const float xs[8] = {x0.x, x0.y, x0.z, x0.w, x1.x, x1.y, x1.z, x1.w};
            bf16x8 hv, lv;
#pragma unroll
            for (int i = 0; i < 8; ++i) {
                const short h = f2bf(xs[i]);
                hv[i] = h;
                if (TERMS == 3) lv[i] = f2bf(xs[i] - bf2f(h));
            }
            *(bf16x8*)&Ahi[srow][scol] = hv;
            if (TERMS == 3) *(bf16x8*)&Alo[srow][scol] = lv;
        }
        *(bf16x8*)&Bhi[bn][bk]     = pb0;
        *(bf16x8*)&Bhi[bn][bk + 8] = pb1;
        *(bf16x8*)&Blo[bn][bk]     = pb2;
        *(bf16x8*)&Blo[bn][bk + 8] = pb3;
        __syncthreads();
        // prefetch next K-tile during compute
        const int kn = k0 + 32;
        if (kn < HID) {
            if (aok) { x0 = *(const float4*)(aptr + kn); x1 = *(const float4*)(aptr + kn + 4); }
            pb0 = *(const bf16x8*)(bhp + kn);
            pb1 = *(const bf16x8*)(bhp + kn + 8);
            pb2 = *(const bf16x8*)(blp + kn);
            pb3 = *(const bf16x8*)(blp + kn + 8);
        }

        const bf16x8 ah0 = *(const bf16x8*)&Ahi[wm * 32 + l15][akk];
        const bf16x8 ah1 = *(const bf16x8*)&Ahi[wm * 32 + 16 + l15][akk];
        bf16x8 al0, al1;
        if (TERMS == 3) {
            al0 = *(const bf16x8*)&Alo[wm * 32 + l15][akk];
            al1 = *(const bf16x8*)&Alo[wm * 32 + 16 + l15][akk];
        }
#pragma unroll
        for (int ni = 0; ni < 8; ++ni) {
            const int col = wn * 128 + ni * 16 + l15;
            const bf16x8 bh = *(const bf16x8*)&Bhi[col][akk];
            const bf16x8 bl = *(const bf16x8*)&Blo[col][akk];
            acc[0][ni] = __builtin_amdgcn_mfma_f32_16x16x32_bf16(ah0, bh, acc[0][ni], 0, 0, 0);
            acc[1][ni] = __builtin_amdgcn_mfma_f32_16x16x32_bf16(ah1, bh, acc[1][ni], 0, 0, 0);
            if (TERMS == 3) {
                acc[0][ni] = __builtin_amdgcn_mfma_f32_16x16x32_bf16(al0, bh, acc[0][ni], 0, 0, 0);
                acc[1][ni] = __builtin_amdgcn_mfma_f32_16x16x32_bf16(al1, bh, acc[1][ni], 0, 0, 0);
            }
            acc[0][ni] = __builtin_amdgcn_mfma_f32_16x16x32_bf16(ah0, bl, acc[0][ni], 0, 0, 0);
            acc[1][ni] = __builtin_amdgcn_mfma_f32_16x16x32_bf16(ah1, bl, acc[1][ni], 0, 0, 0);
        }
    }

    // epilogue: D lane mapping col=lane&15, row=(lane>>4)*4+j  [m89-verified]
    const int ccol0 = wn * 128 + l15;
    const int crow0 = row0 + wm * 32 + (lane >> 4) * 4;
    if (Cf) {
#pragma unroll
        for (int ni = 0; ni < 8; ++ni) {
            const int col = ccol0 + ni * 16;
            const float b = bias ? bias[col] : 0.f;
#pragma unroll
            for (int mi = 0; mi < 2; ++mi) {
#pragma unroll
                for (int j = 0; j < 4; ++j) {
                    const int r = crow0 + mi * 16 + j;
                    if (r < M) Cf[(size_t)r * HID + col] = acc[mi][ni][j] + b;
                }
            }
        }
    } else {
        // kv row (512 shorts): group g: [k4g..k4g+3 | v4g..v4g+3]
#pragma unroll
        for (int ni = 0; ni < 8; ++ni) {
            const int col = ccol0 + ni * 16;
            const int off = (col >> 2) * 8 + (col & 3) + part * 4;
#pragma unroll
            for (int mi = 0; mi < 2; ++mi) {
#pragma unroll
                for (int j = 0; j < 4; ++j) {
                    const int r = crow0 + mi * 16 + j;
                    if (r < M) kvout[(size_t)r * 512 + off] = f2bf(acc[mi][ni][j]);
                }
            }
        }
    }
}

// ---------- small utility ----------
__global__ void zero_kernel(int* __restrict__ p, int n) {
    int i = blockIdx.x * blockDim.x + threadIdx.x;
    if (i < n) p[i] = 0;
}

// ---------- CSR build over dst ----------
__global__ void histogram_kernel(const int* __restrict__ dst, int* __restrict__ counts, int E) {
    int e = blockIdx.x * blockDim.x + threadIdx.x;
    if (e < E) atomicAdd(&counts[dst[e]], 1);
}

#define SCAN_B 1024
__global__ __launch_bounds__(1024) void scan_local(const int* __restrict__ counts,
                                                   int* __restrict__ loc,
                                                   int* __restrict__ bsums, int n) {
    __shared__ int wsum[16];
    const int tid = threadIdx.x, lane = tid & 63, w = tid >> 6;
    const int i = blockIdx.x * SCAN_B + tid;
    const int x = (i < n) ? counts[i] : 0;
    int v = x;
#pragma unroll
    for (int d = 1; d < 64; d <<= 1) {
        int t = __shfl_up(v, d);
        if (lane >= d) v += t;
    }
    if (lane == 63) wsum[w] = v;
    __syncthreads();
    if (tid < 16) {
        int s = wsum[tid];
#pragma unroll
        for (int d = 1; d < 16; d <<= 1) {
            int t = __shfl_up(s, d);
            if (tid >= d) s += t;
        }
        wsum[tid] = s;
    }
    __syncthreads();
    const int excl = ((w == 0) ? 0 : wsum[w - 1]) + (v - x);
    if (i < n) loc[i] = excl;
    if (tid == SCAN_B - 1) bsums[blockIdx.x] = wsum[15];
}
__global__ void scan_bsums(int* __restrict__ bsums, int* __restrict__ total_out, int nb) {
    const int lane = threadIdx.x;
    const int x = (lane < nb) ? bsums[lane] : 0;
    int v = x;
#pragma unroll
    for (int d = 1; d < 64; d <<= 1) {
        int t = __shfl_up(v, d);
        if (lane >= d) v += t;
    }
    if (lane < nb) bsums[lane] = v - x;
    if (lane == 63) total_out[0] = v;
}
__global__ __launch_bounds__(1024) void scan_add(int* __restrict__ loc, const int* __restrict__ bsums,
                                                 int* __restrict__ cursor, int n) {
    const int i = blockIdx.x * SCAN_B + threadIdx.x;
    if (i < n) {
        const int o = loc[i] + bsums[blockIdx.x];
        loc[i] = o;
        cursor[i] = o;
    }
}

__global__ void scatter_kernel(const int* __restrict__ src, const int* __restrict__ dst,
                               int* __restrict__ cursor, int* __restrict__ slot, int E) {
    int e = blockIdx.x * blockDim.x + threadIdx.x;
    if (e < E) {
        const int p = atomicAdd(&cursor[dst[e]], 1);
        slot[p] = src[e];
    }
}

// ---------- per-dst-node attention aggregation (wave per node) ----------
// bf16 packed kv: per edge, ONE contiguous 1KB wave read. Register-pipelined
// quads. q/slot loads and o stores are NON-TEMPORAL to bias L3 toward kv.
__global__ __launch_bounds__(256) void aggregate_kernel(const float* __restrict__ q,
                                                        const short* __restrict__ kv,
                                                        const int* __restrict__ offsets,
                                                        const int* __restrict__ slot,
                                                        float* o_pre, int Ns) {
    const int n    = blockIdx.x * 4 + (threadIdx.x >> 6);
    const int lane = threadIdx.x & 63;
    if (n >= Ns) return;

    const f32x4 q4 = __builtin_nontemporal_load((const f32x4*)&q[(size_t)n * HID + lane * 4]);
    const int e0 = offsets[n], e1 = offsets[n + 1];
    f32x4 acc = (f32x4){0.f, 0.f, 0.f, 0.f};
    float zacc = 0.f;
    const float Cc = 0.25505416631923530f;  // (1/sqrt(32)) * log2(e)
    const float Bb = 7.2134752044448170f;   // 5 * log2(e)
    const size_t loff = (size_t)lane * 8;

    for (int base = e0; base < e1; base += 64) {
        const int chunk = (e1 - base < 64) ? (e1 - base) : 64;
        const int li = (lane < chunk) ? lane : (chunk - 1);
        const int sv = __builtin_nontemporal_load(&slot[base + li]);

        bf16x8 ga[4], gb[4];
        int sa[4], sb[4];
#pragma unroll
        for (int i = 0; i < 4; ++i) {
            sa[i] = __shfl(sv, (0 + i < chunk) ? (0 + i) : 0);
            sb[i] = __shfl(sv, (4 + i < chunk) ? (4 + i) : 0);
        }
#pragma unroll
        for (int i = 0; i < 4; ++i) ga[i] = *(const bf16x8*)(kv + (size_t)sa[i] * 512 + loff);
#pragma unroll
        for (int i = 0; i < 4; ++i) gb[i] = *(const bf16x8*)(kv + (size_t)sb[i] * 512 + loff);

        for (int j = 0; j < chunk; j += 8) {
            // ---- compute quad A (edges j..j+3) ----
            {
                float d[4];
#pragma unroll
                for (int i = 0; i < 4; ++i)
                    d[i] = q4[0] * bf2f(ga[i][0]) + q4[1] * bf2f(ga[i][1]) +
                           q4[2] * bf2f(ga[i][2]) + q4[3] * bf2f(ga[i][3]);
#pragma unroll
                for (int i = 0; i < 4; ++i) {
                    d[i] += __shfl_xor(d[i], 1);
                    d[i] += __shfl_xor(d[i], 2);
                    d[i] += __shfl_xor(d[i], 4);
                }
#pragma unroll
                for (int i = 0; i < 4; ++i) {
                    float sc = exp2f(fminf(fmaxf(d[i] * Cc, -Bb), Bb));
                    sc = (j + i < chunk) ? sc : 0.f;
                    acc[0] += bf2f(ga[i][4]) * sc; acc[1] += bf2f(ga[i][5]) * sc;
                    acc[2] += bf2f(ga[i][6]) * sc; acc[3] += bf2f(ga[i][7]) * sc;
                    zacc += sc;
                }
            }
            // ---- refill A with quad j+8 ----
            if (j + 8 < chunk) {
#pragma unroll
                for (int i = 0; i < 4; ++i)
                    sa[i] = __shfl(sv, (j + 8 + i < chunk) ? (j + 8 + i) : 0);
#pragma unroll
                for (int i = 0; i < 4; ++i) ga[i] = *(const bf16x8*)(kv + (size_t)sa[i] * 512 + loff);
            }
            // ---- compute quad B (edges j+4..j+7) ----
            {
                float d[4];
#pragma unroll
                for (int i = 0; i < 4; ++i)
                    d[i] = q4[0] * bf2f(gb[i][0]) + q4[1] * bf2f(gb[i][1]) +
                           q4[2] * bf2f(gb[i][2]) + q4[3] * bf2f(gb[i][3]);
#pragma unroll
                for (int i = 0; i < 4; ++i) {
                    d[i] += __shfl_xor(d[i], 1);
                    d[i] += __shfl_xor(d[i], 2);
                    d[i] += __shfl_xor(d[i], 4);
                }
#pragma unroll
                for (int i = 0; i < 4; ++i) {
                    float sc = exp2f(fminf(fmaxf(d[i] * Cc, -Bb), Bb));
                    sc = (j + 4 + i < chunk) ? sc : 0.f;
                    acc[0] += bf2f(gb[i][4]) * sc; acc[1] += bf2f(gb[i][5]) * sc;
                    acc[2] += bf2f(gb[i][6]) * sc; acc[3] += bf2f(gb[i][7]) * sc;
                    zacc += sc;
                }
            }
            // ---- refill B with quad j+12 ----
            if (j + 12 < chunk) {
#pragma unroll
                for (int i = 0; i < 4; ++i)
                    sb[i] = __shfl(sv, (j + 12 + i < chunk) ? (j + 12 + i) : 0);
#pragma unroll
                for (int i = 0; i < 4; ++i) gb[i] = *(const bf16x8*)(kv + (size_t)sb[i] * 512 + loff);
            }
        }
    }

    const float inv_z = 1.0f / zacc;
    f32x4 o;
    o[0] = acc[0] * inv_z; o[1] = acc[1] * inv_z; o[2] = acc[2] * inv_z; o[3] = acc[3] * inv_z;
    __builtin_nontemporal_store(o, (f32x4*)&o_pre[(size_t)n * HID + lane * 4]);
}

extern "C" void kernel_launch(void* const* d_in, const int* in_sizes, int n_in,
                              void* d_out, int out_size, void* d_ws, size_t ws_size,
                              hipStream_t stream) {
    const float* context = (const float*)d_in[0];
    const float* node    = (const float*)d_in[1];
    const float* Wq      = (const float*)d_in[2];
    const float* bq      = (const float*)d_in[3];
    const float* Wk      = (const float*)d_in[4];
    const float* Wv      = (const float*)d_in[5];
    const float* Wo      = (const float*)d_in[6];
    const float* bo      = (const float*)d_in[7];
    const int*   src     = (const int*)d_in[8];
    const int*   dst     = (const int*)d_in[9];

    const int Nq = in_sizes[0] / HID;
    const int Ns = in_sizes[1] / HID;
    const int E  = in_sizes[8];
    float* out = (float*)d_out;

    // ---- workspace (~106 MB) ----
    float* q     = (float*)d_ws;                        // Ns*256 f32 (reused as o_pre)
    short* kv    = (short*)(q + (size_t)Ns * HID);      // Nq*512 bf16 (k|v interleaved)
    int* counts  = (int*)(kv + (size_t)Nq * 512);       // Ns   (reused: cursor, then WtO)
    int* offsets = counts + Ns;                         // Ns+1 (+pad)
    int* bsums   = offsets + Ns + 8;                    // 64
    int* slot    = bsums + 64;                          // E    (first 768KB doubles as WtQKV)
    short* WtQKV = (short*)slot;                        // 3 * 131072 shorts
    short* WtO   = (short*)counts;                      // 131072 shorts

    const dim3 blk(256);
    const int  gm = (Ns + 127) / 128;   // Ns == Nq == 50000
    const int  nb = (Ns + SCAN_B - 1) / SCAN_B;

    convw_kernel<<<768, blk, 0, stream>>>(Wq, Wk, Wv, WtQKV);
    gemm_mfma_t<3><<<gm, 512, 0, stream>>>(node,    WtQKV,          bq,      q,       nullptr, 0, Ns);
    gemm_mfma_t<2><<<gm, 512, 0, stream>>>(context, WtQKV + 131072, nullptr, nullptr, kv,      0, Nq);
    gemm_mfma_t<2><<<gm, 512, 0, stream>>>(context, WtQKV + 262144, nullptr, nullptr, kv,      1, Nq);

    zero_kernel<<<(Ns + 255) / 256, blk, 0, stream>>>(counts, Ns);
    histogram_kernel<<<(E + 255) / 256, blk, 0, stream>>>(dst, counts, E);
    scan_local<<<nb, SCAN_B, 0, stream>>>(counts, offsets, bsums, Ns);
    scan_bsums<<<1, 64, 0, stream>>>(bsums, offsets + Ns, nb);
    scan_add<<<nb, SCAN_B, 0, stream>>>(offsets, bsums, counts /*cursor*/, Ns);
    scatter_kernel<<<(E + 255) / 256, blk, 0, stream>>>(src, dst, counts /*cursor*/, slot, E);

    aggregate_kernel<<<(Ns + 3) / 4, blk, 0, stream>>>(q, kv, offsets, slot, q, Ns);

    convw_kernel<<<256, blk, 0, stream>>>(Wo, Wo, Wo, WtO);
    gemm_mfma_t<3><<<gm, 512, 0, stream>>>(q, WtO, bo, out, nullptr, 0, Ns);
}